// Round 1
// baseline (28.133 us; speedup 1.0000x reference)
//
#include <hip/hip_runtime.h>
#include <hip/hip_bf16.h>

// out[b, 4v+k] = x_in[b,v] + (sum_j x_prev[b,4v+j]) - x_prev[b,4v+k]
// One thread handles one (b,v) group of 4 edges as a float4.

__global__ void odd_layer_kernel(const float* __restrict__ x_in,
                                 const float* __restrict__ x_prev,
                                 float* __restrict__ out,
                                 int total_groups) {
    int idx = blockIdx.x * blockDim.x + threadIdx.x;
    int stride = gridDim.x * blockDim.x;
    const float4* __restrict__ pv = reinterpret_cast<const float4*>(x_prev);
    float4* __restrict__ po = reinterpret_cast<float4*>(out);
    for (int g = idx; g < total_groups; g += stride) {
        float4 p = pv[g];
        float s = x_in[g] + p.x + p.y + p.z + p.w;
        float4 o;
        o.x = s - p.x;
        o.y = s - p.y;
        o.z = s - p.z;
        o.w = s - p.w;
        po[g] = o;
    }
}

extern "C" void kernel_launch(void* const* d_in, const int* in_sizes, int n_in,
                              void* d_out, int out_size, void* d_ws, size_t ws_size,
                              hipStream_t stream) {
    const float* x_in   = (const float*)d_in[0];  // [B, V]   = [2048, 2048]
    const float* x_prev = (const float*)d_in[1];  // [B, E]   = [2048, 8192]
    float* out = (float*)d_out;                   // [B, E]

    const int total_groups = out_size / 4;        // B * V = 4,194,304
    const int block = 256;
    int grid = (total_groups + block - 1) / block;
    if (grid > 2048) grid = 2048;                 // grid-stride; 256 CU x 8 blocks
    odd_layer_kernel<<<grid, block, 0, stream>>>(x_in, x_prev, out, total_groups);
}

// Round 2
// 27.563 us; speedup vs baseline: 1.0207x; 1.0207x over previous
//
#include <hip/hip_runtime.h>
#include <hip/hip_bf16.h>

// out[b, 4v+k] = x_in[b,v] + (sum_j x_prev[b,4v+j]) - x_prev[b,4v+k]
// Each thread handles TWO adjacent (b,v) groups per iteration:
//   one float2 from x_in + two independent float4 from x_prev (more MLP).

__global__ void odd_layer_kernel2(const float* __restrict__ x_in,
                                  const float* __restrict__ x_prev,
                                  float* __restrict__ out,
                                  int total_pairs) {
    int idx = blockIdx.x * blockDim.x + threadIdx.x;
    int stride = gridDim.x * blockDim.x;
    const float2* __restrict__ xi2 = reinterpret_cast<const float2*>(x_in);
    const float4* __restrict__ pv  = reinterpret_cast<const float4*>(x_prev);
    float4* __restrict__ po        = reinterpret_cast<float4*>(out);
    for (int t = idx; t < total_pairs; t += stride) {
        int g = t * 2;
        float4 p0 = pv[g];
        float4 p1 = pv[g + 1];
        float2 xi = xi2[t];
        float s0 = xi.x + p0.x + p0.y + p0.z + p0.w;
        float s1 = xi.y + p1.x + p1.y + p1.z + p1.w;
        float4 o0, o1;
        o0.x = s0 - p0.x; o0.y = s0 - p0.y; o0.z = s0 - p0.z; o0.w = s0 - p0.w;
        o1.x = s1 - p1.x; o1.y = s1 - p1.y; o1.z = s1 - p1.z; o1.w = s1 - p1.w;
        po[g]     = o0;
        po[g + 1] = o1;
    }
}

extern "C" void kernel_launch(void* const* d_in, const int* in_sizes, int n_in,
                              void* d_out, int out_size, void* d_ws, size_t ws_size,
                              hipStream_t stream) {
    const float* x_in   = (const float*)d_in[0];  // [B, V]   = [2048, 2048]
    const float* x_prev = (const float*)d_in[1];  // [B, E]   = [2048, 8192]
    float* out = (float*)d_out;                   // [B, E]

    const int total_pairs = out_size / 8;         // B*V/2 = 2,097,152
    const int block = 256;
    int grid = (total_pairs + block - 1) / block;
    if (grid > 2048) grid = 2048;                 // grid-stride; 256 CU x 8 blocks
    odd_layer_kernel2<<<grid, block, 0, stream>>>(x_in, x_prev, out, total_pairs);
}